// Round 6
// baseline (1159.874 us; speedup 1.0000x reference)
//
#include <hip/hip_runtime.h>

typedef unsigned short u16;
typedef __attribute__((ext_vector_type(8))) short short8;   // 8 x bf16 frag (4 VGPRs)
typedef __attribute__((ext_vector_type(4))) float floatx4;  // MFMA accumulator

#define MFMA16(a, b, c) __builtin_amdgcn_mfma_f32_16x16x32_bf16(a, b, c, 0, 0, 0)

// Problem constants
#define BB 16
#define KK 1024
#define NH 1024
#define HD 8
#define DK 128
#define ATT_OFF 16777216      // atted elems (16*1024*1024) before att in d_out

typedef const __attribute__((address_space(1))) unsigned gl_u32;
typedef __attribute__((address_space(3))) unsigned lds_u32;

__device__ __forceinline__ u16 f2bf(float x) {  // RNE f32 -> bf16
  unsigned u = __builtin_bit_cast(unsigned, x);
  u += 0x7fffu + ((u >> 16) & 1u);
  return (u16)(u >> 16);
}

// async global->LDS, 16B per lane; LDS dest must be wave-uniform base (HW adds lane*16)
__device__ __forceinline__ void gload16(const u16* g, u16* l) {
  __builtin_amdgcn_global_load_lds((gl_u32*)g, (lds_u32*)l, 16, 0, 0);
}

// ---------------- input casts: f32 -> bf16, 8 elems/thread, 3 tensors in one launch --
__global__ __launch_bounds__(256) void cast3_bf16x8(
    const float* __restrict__ i0, const float* __restrict__ i1,
    const float* __restrict__ i2, u16* __restrict__ o0, u16* __restrict__ o1,
    u16* __restrict__ o2) {
  const float* in = blockIdx.y == 0 ? i0 : (blockIdx.y == 1 ? i1 : i2);
  u16* out = blockIdx.y == 0 ? o0 : (blockIdx.y == 1 ? o1 : o2);
  const size_t i = ((size_t)blockIdx.x * 256 + threadIdx.x) * 8;
  float4 f0 = *(const float4*)(in + i);
  float4 f1 = *(const float4*)(in + i + 4);
  union { u16 u[8]; uint4 v; } p;
  p.u[0] = f2bf(f0.x); p.u[1] = f2bf(f0.y); p.u[2] = f2bf(f0.z); p.u[3] = f2bf(f0.w);
  p.u[4] = f2bf(f1.x); p.u[5] = f2bf(f1.y); p.u[6] = f2bf(f1.z); p.u[7] = f2bf(f1.w);
  *(uint4*)(out + i) = p.v;
}

// ---------------- weight transpose+cast: 4 weights in one launch (z selects) --------
__global__ __launch_bounds__(256) void tr_w4(
    const float* __restrict__ w0, const float* __restrict__ w1,
    const float* __restrict__ w2, const float* __restrict__ w3,
    u16* __restrict__ o0, u16* __restrict__ o1, u16* __restrict__ o2,
    u16* __restrict__ o3) {
  const int z = blockIdx.z;
  const float* in = z == 0 ? w0 : (z == 1 ? w1 : (z == 2 ? w2 : w3));
  u16* out = z == 0 ? o0 : (z == 1 ? o1 : (z == 2 ? o2 : o3));
  __shared__ u16 t[32][36];
  const int tid = threadIdx.x;
  const int bx = blockIdx.x * 32;  // n base
  const int by = blockIdx.y * 32;  // k base
  const int r = tid >> 3, c4 = (tid & 7) * 4;
  float4 f = *(const float4*)(in + (size_t)(by + r) * 1024 + bx + c4);
  t[r][c4 + 0] = f2bf(f.x);
  t[r][c4 + 1] = f2bf(f.y);
  t[r][c4 + 2] = f2bf(f.z);
  t[r][c4 + 3] = f2bf(f.w);
  __syncthreads();
  union { u16 u[4]; uint2 v; } p;
#pragma unroll
  for (int i = 0; i < 4; i++) p.u[i] = t[c4 + i][r];
  *(uint2*)(out + (size_t)(bx + r) * 1024 + by + c4) = p.v;  // out[n][k] = in[k][n]
}

// ---------------- vv head transpose: vvb bf16 [b,i,h*128+d] -> vvT [bh][d][i] -------
__global__ __launch_bounds__(256) void tr_head(const u16* __restrict__ vvb,
                                               u16* __restrict__ vvT) {
  __shared__ u16 t[32][36];
  const int tid = threadIdx.x;
  const int bh = blockIdx.z, b = bh >> 3, h = bh & 7;
  const int i0 = blockIdx.x * 32, d0 = blockIdx.y * 32;
  const int r = tid >> 3, c4 = (tid & 7) * 4;
  union { u16 u[4]; uint2 v; } p;
  p.v = *(const uint2*)(vvb + (size_t)(b * KK + i0 + r) * NH + h * DK + d0 + c4);
  t[r][c4 + 0] = p.u[0];
  t[r][c4 + 1] = p.u[1];
  t[r][c4 + 2] = p.u[2];
  t[r][c4 + 3] = p.u[3];
  __syncthreads();
#pragma unroll
  for (int i = 0; i < 4; i++) p.u[i] = t[c4 + i][r];
  *(uint2*)(vvT + (size_t)(bh * DK + d0 + r) * KK + i0 + c4) = p.v;
}

// ---------------- MFMA GEMM body: C = A[M,1024-k] * Bt[N,k]^T (+bias) ---------------
// 2-phase pipeline (T3-min): double-buffered LDS, stage tile k+1 BEFORE ds_read+MFMA
// of tile k, ONE barrier per k-step.
__device__ __forceinline__ void gemm_body(
    const u16* __restrict__ Ab, const u16* __restrict__ Bb,
    const float* __restrict__ bias, u16* __restrict__ Cb, float* __restrict__ Cf,
    const int Kd, const int ldc, const int nBase, const int mBase) {
  __shared__ __align__(16) u16 As[2][128 * 32];
  __shared__ __align__(16) u16 Bs[2][128 * 32];
  const int tid = threadIdx.x;
  const int wid = tid >> 6, lane = tid & 63;
  const int wm = (wid & 1) * 64, wn = (wid >> 1) * 64;
  const int lm = lane & 15, lq = lane >> 4;
  const int rIn = lane >> 2;            // row within 16-row group
  const int sSlot = (lane & 3) * 8;     // k-offset in u16

  const u16* aS0 = Ab + (size_t)(mBase + (wid * 2 + 0) * 16 + rIn) * Kd + sSlot;
  const u16* aS1 = Ab + (size_t)(mBase + (wid * 2 + 1) * 16 + rIn) * Kd + sSlot;
  const u16* bS0 = Bb + (size_t)(nBase + (wid * 2 + 0) * 16 + rIn) * Kd + sSlot;
  const u16* bS1 = Bb + (size_t)(nBase + (wid * 2 + 1) * 16 + rIn) * Kd + sSlot;

  floatx4 acc[4][4] = {};

  // prologue: stage k0=0 into buf 0
  gload16(aS0, &As[0][(wid * 2 + 0) * 512]);
  gload16(aS1, &As[0][(wid * 2 + 1) * 512]);
  gload16(bS0, &Bs[0][(wid * 2 + 0) * 512]);
  gload16(bS1, &Bs[0][(wid * 2 + 1) * 512]);
  __syncthreads();

  int cur = 0;
  for (int k0 = 0; k0 < Kd; k0 += 32) {
    const int nxt = cur ^ 1;
    if (k0 + 32 < Kd) {   // issue next-tile stage FIRST (hides under compute)
      gload16(aS0 + k0 + 32, &As[nxt][(wid * 2 + 0) * 512]);
      gload16(aS1 + k0 + 32, &As[nxt][(wid * 2 + 1) * 512]);
      gload16(bS0 + k0 + 32, &Bs[nxt][(wid * 2 + 0) * 512]);
      gload16(bS1 + k0 + 32, &Bs[nxt][(wid * 2 + 1) * 512]);
    }
    short8 af[4], bfr[4];
#pragma unroll
    for (int t = 0; t < 4; t++) {
      af[t]  = *(const short8*)&As[cur][(wm + t * 16 + lm) * 32 + lq * 8];
      bfr[t] = *(const short8*)&Bs[cur][(wn + t * 16 + lm) * 32 + lq * 8];
    }
#pragma unroll
    for (int i = 0; i < 4; i++)
#pragma unroll
      for (int j = 0; j < 4; j++)
        acc[i][j] = MFMA16(af[i], bfr[j], acc[i][j]);
    __syncthreads();  // reads of cur done; next-tile stage drained
    cur = nxt;
  }

  // epilogue: C/D layout col=lane&15, row=(lane>>4)*4+reg
#pragma unroll
  for (int i = 0; i < 4; i++) {
    const int rowL = wm + i * 16 + lq * 4;
#pragma unroll
    for (int j = 0; j < 4; j++) {
      const int col = nBase + wn + j * 16 + lm;
      const float bval = bias ? bias[col] : 0.0f;
      const size_t base = (size_t)(mBase + rowL) * ldc + col;
#pragma unroll
      for (int r = 0; r < 4; r++) {
        const float v = acc[i][j][r] + bval;
        if (Cb) Cb[base + (size_t)r * ldc] = f2bf(v);
        if (Cf) Cf[base + (size_t)r * ldc] = v;
      }
    }
  }
}

// T1 bijective XCD swizzle for the (8,128) grid: XCD x owns mBase stripe [16x,16x+16)
__device__ __forceinline__ int2 swz_grid() {
  const int flat = blockIdx.x + 8 * blockIdx.y;   // 0..1023
  const int xcd = flat & 7, idx = flat >> 3;
  const int nflat = xcd * 128 + idx;
  return make_int2((nflat & 7) * 128, (nflat >> 3) * 128);  // (nBase, mBase)
}

__global__ __launch_bounds__(256, 2) void gemm_bt(
    const u16* __restrict__ A, const u16* __restrict__ Bt,
    const float* __restrict__ bias, u16* __restrict__ Cb, float* __restrict__ Cf) {
  int2 nm = swz_grid();
  gemm_body(A, Bt, bias, Cb, Cf, 1024, 1024, nm.x, nm.y);
}

// Q/K/V projections in ONE launch: grid (8,128,3), z selects tensor
__global__ __launch_bounds__(256, 2) void gemm_qkv(
    const u16* __restrict__ A0, const u16* __restrict__ A1,
    const u16* __restrict__ A2, const u16* __restrict__ B0,
    const u16* __restrict__ B1, const u16* __restrict__ B2,
    const float* __restrict__ b0, const float* __restrict__ b1,
    const float* __restrict__ b2, u16* __restrict__ C0, u16* __restrict__ C1,
    u16* __restrict__ C2) {
  const int z = blockIdx.z;
  const u16* A = z == 0 ? A0 : (z == 1 ? A1 : A2);
  const u16* B = z == 0 ? B0 : (z == 1 ? B1 : B2);
  const float* bias = z == 0 ? b0 : (z == 1 ? b1 : b2);
  u16* C = z == 0 ? C0 : (z == 1 ? C1 : C2);
  int2 nm = swz_grid();
  gemm_body(A, B, bias, C, nullptr, 1024, 1024, nm.x, nm.y);
}

// ---------------- fused scores + mask + softmax + PV ---------------------------------
// Block: one (b,h), 32 query rows (2 row-groups), full 1024 keys. 8 WAVES (512 thr),
// each wave a 128-col slice -> per-wave VGPR state halves (acc[2][8]=64) so the
// kernel fits the 128-VGPR bin => 2 blocks/CU = 16 waves/CU (2x TLP vs 4-wave form)
// at identical per-load arithmetic intensity (every K/V load still feeds 2 MFMAs).
// T5 setprio wraps the MFMA clusters (waves here are phase-staggered, m191 regime).
// att global stores at kernel END (no barrier after -> drain overlaps dispatch tail).
// LDS = exactly 64 KB (P tile 32x1024 bf16); mask/redM/redS alias rows 0-1 (dead
// before P writes; barrier after final redS read protects the alias).
__global__ __launch_bounds__(512, 4) void scores_softmax_pv(
    const u16* __restrict__ qb, const u16* __restrict__ kb,
    const int* __restrict__ mask, const u16* __restrict__ vvT,
    float* __restrict__ att, u16* __restrict__ atp) {
  __shared__ __align__(16) u16 p_lds[32 * 1024];  // 64 KB total
  u16* msk16 = p_lds;                    // [0..1024) u16
  float* redM = (float*)&p_lds[1024];    // 256 f32  [1024..1536)
  float* redS = (float*)&p_lds[1536];    // 256 f32  [1536..2048)
  const int tid = threadIdx.x;

  // grid (32,128): flat 0..4095 round-robins XCDs; XCD x owns bh [16x,16x+16),
  // rowBlk fastest within a bh so kb/vvT slice reuse is temporally tight (L2-hot).
  const int flat = blockIdx.x + 32 * blockIdx.y;
  const int xcd = flat & 7, idx = flat >> 3;       // idx 0..511
  const int bh = xcd * 16 + (idx >> 5);
  const int rowBlk = idx & 31;

  const int b = bh >> 3, h = bh & 7;
  const int wid = tid >> 6, lane = tid & 63;       // wid 0..7
  const int lm = lane & 15, lq = lane >> 4;
  const int rowG = rowBlk * 32;
  const int colW = wid * 128;                      // wave's col base

  {
    int2 m = *(const int2*)(mask + (size_t)b * KK + tid * 2);
    msk16[tid * 2 + 0] = (u16)(m.x != 0);
    msk16[tid * 2 + 1] = (u16)(m.y != 0);
  }

  // q fragments: 2 row-groups x 16 rows x dk=128 (4 k-steps), in regs
  short8 qf[2][4];
#pragma unroll
  for (int g = 0; g < 2; g++) {
    const u16* qp = qb + (size_t)(b * KK + rowG + g * 16 + lm) * NH + h * DK + lq * 8;
#pragma unroll
    for (int ks = 0; ks < 4; ks++) qf[g][ks] = *(const short8*)(qp + ks * 32);
  }

  // ---- QK^T: 8 jt tiles per wave; each K-frag load feeds 2 MFMAs ----
  floatx4 acc[2][8] = {};
  const u16* kpB = kb + (size_t)(b * KK + colW + lm) * NH + h * DK + lq * 8;
#pragma unroll
  for (int jt = 0; jt < 8; jt++) {
    const u16* kp = kpB + (size_t)jt * 16 * NH;
    short8 k0 = *(const short8*)(kp + 0);
    short8 k1 = *(const short8*)(kp + 32);
    short8 k2 = *(const short8*)(kp + 64);
    short8 k3 = *(const short8*)(kp + 96);
    floatx4 a0 = acc[0][jt], a1 = acc[1][jt];
    __builtin_amdgcn_s_setprio(1);
    a0 = MFMA16(qf[0][0], k0, a0);
    a1 = MFMA16(qf[1][0], k0, a1);
    a0 = MFMA16(qf[0][1], k1, a0);
    a1 = MFMA16(qf[1][1], k1, a1);
    a0 = MFMA16(qf[0][2], k2, a0);
    a1 = MFMA16(qf[1][2], k2, a1);
    a0 = MFMA16(qf[0][3], k3, a0);
    a1 = MFMA16(qf[1][3], k3, a1);
    __builtin_amdgcn_s_setprio(0);
    acc[0][jt] = a0;
    acc[1][jt] = a1;
  }
  __syncthreads();  // msk stores complete

  const float scale = 0.08838834764831845f;  // 1/sqrt(128)
  float mrow[2][4];
#pragma unroll
  for (int g = 0; g < 2; g++)
#pragma unroll
    for (int r = 0; r < 4; r++) mrow[g][r] = -3e38f;
#pragma unroll
  for (int jt = 0; jt < 8; jt++) {
    const int col = colW + jt * 16 + lm;
    const bool mk = msk16[col] != 0;
#pragma unroll
    for (int g = 0; g < 2; g++)
#pragma unroll
      for (int r = 0; r < 4; r++) {
        float s = mk ? -1e9f : acc[g][jt][r] * scale;
        acc[g][jt][r] = s;
        mrow[g][r] = fmaxf(mrow[g][r], s);
      }
  }
  // reduce max over the 16 lanes holding this row's cols
#pragma unroll
  for (int off = 1; off < 16; off <<= 1)
#pragma unroll
    for (int g = 0; g < 2; g++)
#pragma unroll
      for (int r = 0; r < 4; r++)
        mrow[g][r] = fmaxf(mrow[g][r], __shfl_xor(mrow[g][r], off));
  if (lm == 0) {
#pragma unroll
    for (int g = 0; g < 2; g++)
#pragma unroll
      for (int r = 0; r < 4; r++)
        redM[wid * 32 + g * 16 + lq * 4 + r] = mrow[g][r];
  }
  __syncthreads();
#pragma unroll
  for (int g = 0; g < 2; g++)
#pragma unroll
    for (int r = 0; r < 4; r++) {
      const int e = g * 16 + lq * 4 + r;
      float m = redM[e];
#pragma unroll
      for (int w = 1; w < 8; w++) m = fmaxf(m, redM[w * 32 + e]);
      mrow[g][r] = m;
    }

  float srow[2][4] = {};
#pragma unroll
  for (int jt = 0; jt < 8; jt++)
#pragma unroll
    for (int g = 0; g < 2; g++)
#pragma unroll
      for (int r = 0; r < 4; r++) {
        float e = __expf(acc[g][jt][r] - mrow[g][r]);
        acc[g][jt][r] = e;
        srow[g][r] += e;
      }
#pragma unroll
  for (int off = 1; off < 16; off <<= 1)
#pragma unroll
    for (int g = 0; g < 2; g++)
#pragma unroll
      for (int r = 0; r < 4; r++) srow[g][r] += __shfl_xor(srow[g][r], off);
  if (lm == 0) {
#pragma unroll
    for (int g = 0; g < 2; g++)
#pragma unroll
      for (int r = 0; r < 4; r++)
        redS[wid * 32 + g * 16 + lq * 4 + r] = srow[g][r];
  }
  __syncthreads();
#pragma unroll
  for (int g = 0; g < 2; g++)
#pragma unroll
    for (int r = 0; r < 4; r++) {
      const int e = g * 16 + lq * 4 + r;
      float s = redS[e];
#pragma unroll
      for (int w = 1; w < 8; w++) s += redS[w * 32 + e];
      srow[g][r] = 1.0f / s;
    }
  __syncthreads();  // alias protection: redS reads done before p_lds writes below

  // normalize in-place (acc keeps p for the end-of-kernel att stores) and write
  // the bf16 P tile to swizzled LDS: idx = (row*1024 + col) ^ ((row&7)<<3).
#pragma unroll
  for (int g = 0; g < 2; g++)
#pragma unroll
    for (int r = 0; r < 4; r++) {
      const int row = g * 16 + lq * 4 + r;
#pragma unroll
      for (int jt = 0; jt < 8; jt++) {
        const int col = colW + jt * 16 + lm;
        const float p = acc[g][jt][r] * srow[g][r];
        acc[g][jt][r] = p;
        p_lds[(row * 1024 + col) ^ ((row & 7) << 3)] = f2bf(p);
      }
    }
  __syncthreads();  // P tile complete (LDS-only drain; no global stores pending)

  // ---- PV: out 32 rows x 128 d; wave wid owns d-rows [wid*16, wid*16+16).
  // Each V load feeds 2 MFMAs (row-groups); even/odd acc split breaks dep chains.
  floatx4 p0a = {}, p0b = {}, p1a = {}, p1b = {};
  const u16* vBase = vvT + (size_t)bh * DK * KK + (size_t)(wid * 16 + lm) * KK + lq * 8;
#pragma unroll 8
  for (int s = 0; s < 32; s++) {
    short8 vv = *(const short8*)(vBase + s * 32);
    short8 pf0 = *(const short8*)&p_lds[((0 + lm) * 1024 + s * 32 + lq * 8) ^ ((lm & 7) << 3)];
    short8 pf1 = *(const short8*)&p_lds[((16 + lm) * 1024 + s * 32 + lq * 8) ^ ((lm & 7) << 3)];
    __builtin_amdgcn_s_setprio(1);
    if (s & 1) {
      p0b = MFMA16(pf0, vv, p0b);
      p1b = MFMA16(pf1, vv, p1b);
    } else {
      p0a = MFMA16(pf0, vv, p0a);
      p1a = MFMA16(pf1, vv, p1a);
    }
    __builtin_amdgcn_s_setprio(0);
  }
  floatx4 o0 = p0a + p0b;  // row-group 0
  floatx4 o1 = p1a + p1b;  // row-group 1

  // atp epilogue: C layout col(d)=lm, row=lq*4+r
#pragma unroll
  for (int r = 0; r < 4; r++) {
    const int row0 = rowG + 0 + lq * 4 + r;
    const int row1 = rowG + 16 + lq * 4 + r;
    atp[(size_t)(b * KK + row0) * NH + h * DK + wid * 16 + lm] = f2bf(o0[r]);
    atp[(size_t)(b * KK + row1) * NH + h * DK + wid * 16 + lm] = f2bf(o1[r]);
  }

  // att stores LAST (nontemporal, write-once output): no barrier follows, so the
  // store drain overlaps the dispatch tail instead of serializing mid-kernel.
#pragma unroll
  for (int g = 0; g < 2; g++)
#pragma unroll
    for (int r = 0; r < 4; r++) {
      const int row = g * 16 + lq * 4 + r;
      float* attRow = att + ((size_t)bh * KK + rowG + row) * KK;
#pragma unroll
      for (int jt = 0; jt < 8; jt++) {
        const int col = colW + jt * 16 + lm;
        __builtin_nontemporal_store(acc[g][jt][r], attRow + col);
      }
    }
}

// ---------------- launcher ----------------------------------------------------------
extern "C" void kernel_launch(void* const* d_in, const int* in_sizes, int n_in,
                              void* d_out, int out_size, void* d_ws, size_t ws_size,
                              hipStream_t stream) {
  const float* v     = (const float*)d_in[0];
  const float* key   = (const float*)d_in[1];
  const float* query = (const float*)d_in[2];
  const int*   mask  = (const int*)d_in[3];
  const float* Wq = (const float*)d_in[4];
  const float* bq = (const float*)d_in[5];
  const float* Wk = (const float*)d_in[6];
  const float* bk = (const float*)d_in[7];
  const float* Wv = (const float*)d_in[8];
  const float* bv = (const float*)d_in[9];
  const float* Wm = (const float*)d_in[10];
  const float* bm = (const float*)d_in[11];

  float* atted = (float*)d_out;
  float* att   = atted + (size_t)ATT_OFF;

  // workspace layout (bytes): ~176 MB, unchanged
  char* ws = (char*)d_ws;
  u16* qb   = (u16*)(ws + 0);
  u16* kb   = (u16*)(ws + 33554432ll);
  u16* vvb  = (u16*)(ws + 67108864ll);
  u16* vvT  = (u16*)(ws + 100663296ll);
  u16* atp  = (u16*)(ws + 134217728ll);
  u16* WqT  = (u16*)(ws + 167772160ll);
  u16* WkT  = (u16*)(ws + 169869312ll);
  u16* WvT  = (u16*)(ws + 171966464ll);
  u16* WmT  = (u16*)(ws + 174063616ll);

  // bf16 copies of raw inputs live in the (not yet written) att region of d_out:
  // all dead before scores_softmax_pv overwrites att. Zero workspace growth.
  u16* cq = (u16*)att;
  u16* ck = cq + 16777216;
  u16* cv = ck + 16777216;

  // 0) input casts f32 -> bf16 (16M elems each, 8/thread), one launch
  cast3_bf16x8<<<dim3(8192, 3), 256, 0, stream>>>(query, key, v, cq, ck, cv);

  // 1) weight transposes (f32 -> bf16, [k][n] -> [n][k]), one launch
  tr_w4<<<dim3(32, 32, 4), 256, 0, stream>>>(Wq, Wk, Wv, Wm, WqT, WkT, WvT, WmT);

  // 2) Q/K/V projections in one launch: [16384,1024] x [1024,1024] -> bf16
  gemm_qkv<<<dim3(8, 128, 3), 256, 0, stream>>>(cq, ck, cv, WqT, WkT, WvT,
                                                bq, bk, bv, qb, kb, vvb);

  // 3) vv -> vvT[bh][d][k]
  tr_head<<<dim3(32, 4, 128), 256, 0, stream>>>(vvb, vvT);

  // 4) fused scores + mask + softmax -> att (f32) AND att@vv -> atp (bf16)
  scores_softmax_pv<<<dim3(32, 128), 512, 0, stream>>>(qb, kb, mask, vvT, att, atp);

  // 5) output projection: atp bf16 [16384,1024] x WmT -> atted f32
  gemm_bt<<<dim3(8, 128), 256, 0, stream>>>(atp, WmT, bm, nullptr, atted);
}